// Round 1
// baseline (33.860 us; speedup 1.0000x reference)
//
#include <hip/hip_runtime.h>

// PerPixelConv: out[b,0,h,w] = sum_{kw,kh} kernel[b, kw*3+kh, h, w] * padded_img[b, h+kh, w+kw]
// B=16, K2=9 (k=3, pad=1), H=W=512, fp32. Memory-bound: kernel tensor (151 MB) dominates.

#define PPC_B 16
#define PPC_K2 9
#define PPC_H 512
#define PPC_W 512

__global__ __launch_bounds__(256) void PerPixelConv_kernel(
    const float* __restrict__ kern,   // [B, 9, H, W]
    const float* __restrict__ img,    // [B, 1, H, W]
    float* __restrict__ out)          // [B, 1, H, W]
{
    const int W4 = PPC_W / 4;                       // 128 float4 per row
    const int total = PPC_B * PPC_H * W4;           // 1,048,576 threads
    int gid = blockIdx.x * blockDim.x + threadIdx.x;
    if (gid >= total) return;

    const int w4 = (gid % W4) * 4;                  // starting w of this thread's 4 pixels
    const int h  = (gid / W4) % PPC_H;
    const int b  = gid / (W4 * PPC_H);

    const size_t plane = (size_t)PPC_H * PPC_W;     // 262144
    const float* kb = kern + (size_t)b * PPC_K2 * plane;
    const float* ib = img  + (size_t)b * plane;

    // Load 3x6 image neighborhood: rows h-1..h+1, cols w4-1..w4+4 (zero-padded).
    float im[3][6];
#pragma unroll
    for (int r = 0; r < 3; ++r) {
        const int ih = h + r - 1;
        const bool rv = (ih >= 0) && (ih < PPC_H);
        const float* row = ib + (size_t)ih * PPC_W;
#pragma unroll
        for (int c = 0; c < 6; ++c) {
            const int iw = w4 + c - 1;
            const bool cv = (iw >= 0) && (iw < PPC_W);
            im[r][c] = (rv && cv) ? row[iw] : 0.0f;
        }
    }

    float4 acc = make_float4(0.f, 0.f, 0.f, 0.f);
#pragma unroll
    for (int kw = 0; kw < 3; ++kw) {
#pragma unroll
        for (int kh = 0; kh < 3; ++kh) {
            const int idx = kw * 3 + kh;
            const float4 kv = *reinterpret_cast<const float4*>(
                kb + (size_t)idx * plane + (size_t)h * PPC_W + w4);
            // output pixel (h, w4+j) uses image[h+kh-1][w4+j+kw-1] = im[kh][j+kw]
            acc.x = fmaf(kv.x, im[kh][0 + kw], acc.x);
            acc.y = fmaf(kv.y, im[kh][1 + kw], acc.y);
            acc.z = fmaf(kv.z, im[kh][2 + kw], acc.z);
            acc.w = fmaf(kv.w, im[kh][3 + kw], acc.w);
        }
    }

    *reinterpret_cast<float4*>(out + (size_t)b * plane + (size_t)h * PPC_W + w4) = acc;
}

extern "C" void kernel_launch(void* const* d_in, const int* in_sizes, int n_in,
                              void* d_out, int out_size, void* d_ws, size_t ws_size,
                              hipStream_t stream) {
    const float* kern = (const float*)d_in[0];  // [16, 9, 512, 512]
    const float* img  = (const float*)d_in[1];  // [16, 1, 512, 512]
    float* out = (float*)d_out;                 // [16, 1, 512, 512]

    const int total = PPC_B * PPC_H * (PPC_W / 4);
    const int block = 256;
    const int grid = (total + block - 1) / block;   // 4096 blocks
    PerPixelConv_kernel<<<grid, block, 0, stream>>>(kern, img, out);
}